// Round 14
// baseline (305.845 us; speedup 1.0000x reference)
//
#include <hip/hip_runtime.h>
#include <hip/hip_fp16.h>
#include <hip/hip_cooperative_groups.h>
#include <math.h>

namespace cg = cooperative_groups;

// Problem constants (fixed by reference setup_inputs)
#define BB 4096
#define LL 16
#define DD 512

// Marginal lookup table: 16 latents x NPTS points over [XMIN, XMIN+XRANGE]
#define NPTS   1024
#define XMIN   -6.0f
#define XRANGE 12.0f

#define LOG2E_F  1.4426950408889634f
#define LN2_F    0.6931471805599453f
#define LOG2PI_F 1.8378770664093453f

// Schraudolph f32 exp2 for the joint: w = 2^23*(lp2sum + BIASF); cvt_u32
// saturates negatives to 0; bits reinterpreted as f32 ~ 2^lp2sum.
#define OFFC     22.942540f
#define SCALE23  8388608.0f
#define BIASF    126.94269504f

#if __has_builtin(__builtin_amdgcn_exp2f)
#define EXP2(x) __builtin_amdgcn_exp2f(x)
#else
#define EXP2(x) exp2f(x)
#endif
#if __has_builtin(__builtin_amdgcn_logf)
#define LOG2(x) __builtin_amdgcn_logf(x)
#else
#define LOG2(x) log2f(x)
#endif

typedef float f32x2 __attribute__((ext_vector_type(2)));

// ws float layout:
//   cj   [0      , 147456)  4096 j * 36: A[16] B[16] Csum pad3 (S-scaled)
//   ct   [147456 , 344064)  raw coefs transposed [part 3][l 16][j 4096]
//   rp   [344064 , 346112)  512 recon block partials (pre-scaled)
//   klp  [346112 , 346368)  256 KL block partials (pre-scaled)
//   tp   [346368 , 870656)  table partials [jc 32][l 16][g 1024]
//   tab  [870656 , 887040)  marginal table [l 16][g 1024]
//   jp   [887040 , 1411328) joint partials TRANSPOSED [i 4096][chunk 128]
#define CJ_F   0
#define CT_F   147456
#define RP_F   344064
#define KLP_F  346112
#define TP_F   346368
#define TAB_F  870656
#define JP_F   887040

// Block-level sum reduction; result valid on thread 0. Re-entrant.
__device__ __forceinline__ float block_reduce(float v) {
  __shared__ float sm[4];
  __syncthreads();
#pragma unroll
  for (int off = 32; off; off >>= 1) v += __shfl_xor(v, off);
  if ((threadIdx.x & 63) == 0) sm[threadIdx.x >> 6] = v;
  __syncthreads();
  if (threadIdx.x == 0) v = (sm[0] + sm[1]) + (sm[2] + sm[3]);
  return v;
}

// ---------------------------------------------------------------------------
// MEGA KERNEL (cooperative, grid 512 x 256, 2 blocks/CU co-resident).
// R13 post-mortem: pk_fma halved the joint loop's instructions -> total moved
// 1.2us. Joint was never the binder; the ~35us unaccounted in the budget
// (fill 42.5 + modeled kernels ~30 vs 117.9 measured) scales with DISPATCH
// COUNT (R10 4-kernel: ~14us unaccounted; R13 6-kernel: ~35us) -> per-launch
// overhead ~5-7us dominates. Fix: ONE cooperative kernel, phases separated by
// grid.sync() (harness-supported per guide). Phases:
//   P0 prep (recon grid-stride, coef cj/ct, KL)        all 512 blocks
//   P1 table build (exact v_exp_f32)                   512 = 32jc x 16l
//   P2 table reduce                                    blocks 0..63
//   P3 joint (pk_fma, R=4, CHUNK=32)                   all 512 (4bx x 128by)
//   P4 final (jp sum via float4 [i][chunk] layout, L2 table gathers, logs)
//                                                      blocks 0..15
// ---------------------------------------------------------------------------
__global__ __launch_bounds__(256, 2) void mega_kernel(
    const float4* __restrict__ data4, const float4* __restrict__ recon4,
    const float* __restrict__ zm, const float* __restrict__ zlv,
    const float* __restrict__ z,
    float* __restrict__ cj, float* __restrict__ ct,
    float* __restrict__ rp, float* __restrict__ klp,
    float* __restrict__ tp, float* __restrict__ tab,
    float* __restrict__ jp, float* __restrict__ out) {
  cg::grid_group grid = cg::this_grid();
  const int tid = threadIdx.x;
  const int b = blockIdx.x;

  // ================= P0: prep =================
  if (b == 0 && tid == 0) out[0] = 0.0f;
  {
    const int n4 = (BB * DD) / 4;
    float s = 0.0f;
    for (int k = b * 256 + tid; k < n4; k += 512 * 256) {
      float4 a = data4[k];
      float4 r = recon4[k];
      s += (fabsf(a.x - r.x) + fabsf(a.y - r.y)) +
           (fabsf(a.z - r.z) + fabsf(a.w - r.w));
    }
    float t = block_reduce(s);
    if (tid == 0) rp[b] = t * (1.0f / (float)(BB * DD));
  }
  if (b < 256) {
    const float S = 1024.0f / 65535.0f;
    int idx = b * 256 + tid;
    int j = idx >> 4;
    int l = idx & 15;
    float m = zm[idx];
    float lv = zlv[idx];
    float inv = EXP2(-lv * LOG2E_F);           // e^{-lv}
    float a = -0.5f * LOG2E_F * inv;           // log2-domain quadratic coef
    float c2 = -0.5f * LOG2E_F * (lv + LOG2PI_F);
    float braw = -2.0f * a * m;
    float craw = fmaf(a, m * m, c2);

    cj[j * 36 + l]      = a * S;
    cj[j * 36 + 16 + l] = braw * S;
    float cs = (craw + OFFC) * S;
    cs += __shfl_xor(cs, 1); cs += __shfl_xor(cs, 2);
    cs += __shfl_xor(cs, 4); cs += __shfl_xor(cs, 8);
    if (l == 0) cj[j * 36 + 32] = cs;

    ct[(0 * 16 + l) * 4096 + j] = a;
    ct[(1 * 16 + l) * 4096 + j] = braw;
    ct[(2 * 16 + l) * 4096 + j] = craw;

    float kls = m * m + EXP2(lv * LOG2E_F) - lv - 1.0f;
    float s = block_reduce(kls);
    if (tid == 0) klp[b] = s * (0.5f / (float)BB);
  }
  grid.sync();

  // ================= P1: marginal table build =================
  {
    __shared__ float la[128], lb[128], lc[128];
    const int jc = b >> 4;   // 0..31
    const int l  = b & 15;   // 0..15
    const int j0 = jc * 128;
    if (tid < 128) {
      la[tid] = ct[(0 * 16 + l) * 4096 + j0 + tid];
      lb[tid] = ct[(1 * 16 + l) * 4096 + j0 + tid];
      lc[tid] = ct[(2 * 16 + l) * 4096 + j0 + tid];
    }
    const float H = XRANGE / (float)(NPTS - 1);
    float x[4], acc[4];
#pragma unroll
    for (int k = 0; k < 4; ++k) {
      x[k] = XMIN + (float)(k * 256 + tid) * H;
      acc[k] = 0.0f;
    }
    __syncthreads();
#pragma unroll 2
    for (int j = 0; j < 128; ++j) {
      float a = la[j], bb = lb[j], c = lc[j];
#pragma unroll
      for (int k = 0; k < 4; ++k) {
        float lp = fmaf(fmaf(a, x[k], bb), x[k], c);
        acc[k] += EXP2(lp);
      }
    }
    float* o = tp + ((size_t)jc * 16 + l) * NPTS;
#pragma unroll
    for (int k = 0; k < 4; ++k) o[k * 256 + tid] = acc[k];
  }
  grid.sync();

  // ================= P2: table reduce (blocks 0..63) =================
  if (b < 64) {
    const int e = b * 256 + tid;
    float s = 0.0f;
#pragma unroll 4
    for (int jc = 0; jc < 32; ++jc) s += tp[(size_t)jc * (16 * NPTS) + e];
    tab[e] = s;
  }

  // ================= P3: joint (pk_fma) =================
  {
    __shared__ float lcj[32 * 36];
    const int bx = b & 3;       // 0..3
    const int by = b >> 2;      // 0..127
    const int i0 = bx * 1024 + tid;
    const int j0 = by * 32;
    const float JMUL = 65535.0f * 8192.0f;
    const float JK   = -SCALE23 * (16.0f * OFFC - BIASF);

    {
      const float4* g4 = (const float4*)(cj + (size_t)j0 * 36);
      float4* l4 = (float4*)lcj;
      for (int t = tid; t < (32 * 36) / 4; t += 256) l4[t] = g4[t];
    }

    f32x2 zv[4][8];
#pragma unroll
    for (int r = 0; r < 4; ++r) {
      const float4* zp = (const float4*)(z + (size_t)(i0 + 256 * r) * 16);
#pragma unroll
      for (int q = 0; q < 4; ++q) {
        float4 v = zp[q];
        zv[r][2 * q]     = (f32x2){v.x, v.y};
        zv[r][2 * q + 1] = (f32x2){v.z, v.w};
      }
    }
    // Pin: compiler otherwise sinks z loads into the j-loop (R4 lesson).
#pragma unroll
    for (int r = 0; r < 4; ++r)
#pragma unroll
      for (int p = 0; p < 8; ++p) asm volatile("" : "+v"(zv[r][p]));

    float accJ[4] = {0.0f, 0.0f, 0.0f, 0.0f};

    __syncthreads();

#pragma unroll 2
    for (int j = 0; j < 32; ++j) {
      const float* cp = lcj + j * 36;
      f32x2 A[8], Bv[8];
#pragma unroll
      for (int t = 0; t < 4; ++t) {  // 8x ds_read_b128
        *(float4*)&A[2 * t]  = *(const float4*)(cp + 4 * t);
        *(float4*)&Bv[2 * t] = *(const float4*)(cp + 16 + 4 * t);
      }
      float Cs = cp[32];             // 1x ds_read_b32
#pragma unroll
      for (int r = 0; r < 4; ++r) {
        f32x2 acc = (f32x2){0.0f, 0.0f};
#pragma unroll
        for (int p = 0; p < 8; ++p) {
          f32x2 t2;
          asm("v_pk_fma_f32 %0, %1, %2, %3"
              : "=v"(t2) : "v"(A[p]), "v"(zv[r][p]), "v"(Bv[p]));
          asm("v_pk_fma_f32 %0, %1, %2, %0"
              : "+v"(acc) : "v"(t2), "v"(zv[r][p]));
        }
        float js = (acc.x + acc.y) + Cs;   // S*(sum_l lp2 + 16*OFFC)
        float w = fmaf(js, JMUL, JK);      // 2^23*(sum lp2 + BIASF)
        unsigned u;
        asm("v_cvt_u32_f32 %0, %1" : "=v"(u) : "v"(w));  // neg sat to 0
        accJ[r] += __uint_as_float(u);
      }
    }

    // Transposed store [i][chunk]: scatter writes (L2 absorbs ~2MB), so the
    // final phase reads each row as 32 contiguous float4s.
#pragma unroll
    for (int r = 0; r < 4; ++r)
      jp[(size_t)(i0 + 256 * r) * 128 + by] = accJ[r];
  }
  grid.sync();

  // ================= P4: final (blocks 0..15) =================
  if (b < 16) {
    const int i = b * 256 + tid;

    float s0 = 0.0f, s1 = 0.0f, s2 = 0.0f, s3 = 0.0f;
    const float4* jr = (const float4*)(jp + (size_t)i * 128);
#pragma unroll 8
    for (int c = 0; c < 32; ++c) {
      float4 v = jr[c];
      s0 += v.x; s1 += v.y; s2 += v.z; s3 += v.w;
    }
    float lg = LOG2((s0 + s1) + (s2 + s3));  // log2 S_joint

    const float4* zp = (const float4*)(z + (size_t)i * 16);
    const float SC = (float)(NPTS - 1) / XRANGE;
#pragma unroll
    for (int q = 0; q < 4; ++q) {
      float4 v = zp[q];
      float xs[4] = {v.x, v.y, v.z, v.w};
#pragma unroll
      for (int k = 0; k < 4; ++k) {
        int l = 4 * q + k;
        float t = (xs[k] - XMIN) * SC;
        t = fminf(fmaxf(t, 0.0f), (float)(NPTS - 2) + 0.999f);
        int g = (int)t;
        float f = t - (float)g;
        float m0 = tab[l * NPTS + g];       // L2-resident 64KB table
        float m1 = tab[l * NPTS + g + 1];
        lg -= LOG2(fmaf(f, m1 - m0, m0));
      }
    }

    float tval = lg * (LN2_F / (float)BB);
    if (b == 0) {
      tval += rp[tid] + rp[tid + 256];  // 512 recon partials
      tval += klp[tid];
    }
    float s = block_reduce(tval);
    if (tid == 0) atomicAdd(out, s);
  }
}

extern "C" void kernel_launch(void* const* d_in, const int* in_sizes, int n_in,
                              void* d_out, int out_size, void* d_ws, size_t ws_size,
                              hipStream_t stream) {
  const float4* data4  = (const float4*)d_in[0];
  const float4* recon4 = (const float4*)d_in[1];
  const float* z       = (const float*)d_in[2];
  const float* zm      = (const float*)d_in[3];
  const float* zlv     = (const float*)d_in[4];
  float* out = (float*)d_out;
  float* ws  = (float*)d_ws;

  float* cj  = ws + CJ_F;
  float* ct  = ws + CT_F;
  float* rp  = ws + RP_F;
  float* klp = ws + KLP_F;
  float* tp  = ws + TP_F;
  float* tab = ws + TAB_F;
  float* jp  = ws + JP_F;

  void* args[] = {
      (void*)&data4, (void*)&recon4, (void*)&zm, (void*)&zlv, (void*)&z,
      (void*)&cj, (void*)&ct, (void*)&rp, (void*)&klp,
      (void*)&tp, (void*)&tab, (void*)&jp, (void*)&out};

  hipLaunchCooperativeKernel((const void*)mega_kernel, dim3(512), dim3(256),
                             args, 0, stream);
}

// Round 15
// 117.236 us; speedup vs baseline: 2.6088x; 2.6088x over previous
//
#include <hip/hip_runtime.h>
#include <hip/hip_fp16.h>
#include <math.h>

// Problem constants (fixed by reference setup_inputs)
#define BB 4096
#define LL 16
#define DD 512

#define LOG2E_F  1.4426950408889634f
#define LN2_F    0.6931471805599453f
#define LOG2PI_F 1.8378770664093453f

// f16-Schraudolph via pknorm: coefs scaled by S=1024/65535 with offset OFFC
// folded in. pknorm_u16(lp_n) = round(1024*(lp2+OFFC)) = f16 bits of
// 2^(lp2 + OFFC-15) (OFFC=23 -> 2^(lp2+8)); negatives clamp to 0.
#define OFFC     22.942540f
#define SCALE23  8388608.0f
#define BIASF    126.94269504f

#if __has_builtin(__builtin_amdgcn_exp2f)
#define EXP2(x) __builtin_amdgcn_exp2f(x)
#else
#define EXP2(x) exp2f(x)
#endif
#if __has_builtin(__builtin_amdgcn_logf)
#define LOG2(x) __builtin_amdgcn_logf(x)
#else
#define LOG2(x) log2f(x)
#endif

typedef float f32x2 __attribute__((ext_vector_type(2)));

// ws float layout (nc = 128):
//   coef    [0      , 196608)   4096 j * 48  (A[16] B[16] C[16], S-scaled)
//   rp      [196608 , 198656)   2048 recon block partials (pre-scaled)
//   klp     [198656 , 198912)   256 KL block partials (pre-scaled)
//   partial [268544 , +nc*9*4096)  packed tc partials (8 f16-pair words + joint)
//   red2    [.. , +G*17*BB)        group sums (G = nc/16), k-major
#define COEF_F   0
#define RP_F     196608
#define KLP_F    198656
#define PART_F   268544

// Block-level sum reduction; result valid on thread 0. Re-entrant.
__device__ __forceinline__ float block_reduce(float v) {
  __shared__ float sm[4];
  __syncthreads();
#pragma unroll
  for (int off = 32; off; off >>= 1) v += __shfl_xor(v, off);
  if ((threadIdx.x & 63) == 0) sm[threadIdx.x >> 6] = v;
  __syncthreads();
  if (threadIdx.x == 0) v = (sm[0] + sm[1]) + (sm[2] + sm[3]);
  return v;
}

// ---------------------------------------------------------------------------
// Kernel A: recon partials + coef prep + KL partials + out zero.
// Expanded-quadratic coefs: lp' = (A*z + B)*z + C = S*(lp2 + OFFC)
// ---------------------------------------------------------------------------
__global__ __launch_bounds__(256) void prep_recon_kernel(
    const float4* __restrict__ data4, const float4* __restrict__ recon4,
    const float* __restrict__ zm, const float* __restrict__ zlv,
    float* __restrict__ coef, float* __restrict__ rp,
    float* __restrict__ klp, float* __restrict__ out) {
  const int tid = threadIdx.x;
  const int b = blockIdx.x;

  if (b == 1024 && tid == 0) out[0] = 0.0f;

  {
    const int n4 = (BB * DD) / 4;
    int stride = gridDim.x * 256;
    float s = 0.0f;
    for (int k = b * 256 + tid; k < n4; k += stride) {
      float4 a = data4[k];
      float4 r = recon4[k];
      s += (fabsf(a.x - r.x) + fabsf(a.y - r.y)) +
           (fabsf(a.z - r.z) + fabsf(a.w - r.w));
    }
    float t = block_reduce(s);
    if (tid == 0) rp[b] = t * (1.0f / (float)(BB * DD));
  }

  if (b < 256) {
    const float S = 1024.0f / 65535.0f;
    int idx = b * 256 + tid;
    int j = idx >> 4;
    int l = idx & 15;
    float m = zm[idx];
    float lv = zlv[idx];
    float inv = EXP2(-lv * LOG2E_F);
    float a = -0.5f * LOG2E_F * inv;
    float c2 = -0.5f * LOG2E_F * (lv + LOG2PI_F);
    coef[j * 48 + l]      = a * S;                            // A
    coef[j * 48 + 16 + l] = -2.0f * a * m * S;                // B
    coef[j * 48 + 32 + l] = (fmaf(a, m * m, c2) + OFFC) * S;  // C

    float kls = m * m + EXP2(lv * LOG2E_F) - lv - 1.0f;
    float s = block_reduce(kls);
    if (tid == 0) klp[b] = s * (0.5f / (float)BB);
  }
}

// One j's coefs as 24 f32 pairs: A pairs [0..8), B [8..16), C [16..24).
struct C48 { f32x2 v[24]; };

__device__ __forceinline__ void ldcoef(C48& b, const float* cp) {
#pragma unroll
  for (int t = 0; t < 12; ++t)  // 12x ds_read_b128
    *(float4*)&b.v[2 * t] = *(const float4*)(cp + 4 * t);
}

union HU { unsigned u; __half2 h; };

// ---------------------------------------------------------------------------
// Kernel B: TC partial sums. R=4 rows/thread, CHUNK=32, packed VOP3P math,
// explicit double-buffered coef prefetch. Best measured config (R10: total
// 116.8us). Session learnings baked in:
//  - j-loop wall time is ~invariant to instruction count (pk null, R13) and
//    to memory path (LDS/SMEM), occupancy, and amortization — do not expect
//    instruction-level rewrites to move it.
//  - zv pins (volatile asm) required: compiler otherwise sinks z loads into
//    the loop (R4, VGPR=80 signature).
//  - (256,2) bound: VGPR headroom for the C48 double buffers (no spill; R7's
//    spill signature was VGPR_Count << live set + GB-scale FETCH_SIZE).
//  - CHUNK=32/nc=128 packed store: 18.9 MB partial traffic.
// ---------------------------------------------------------------------------
template <int CHUNK, int R>
__device__ __forceinline__ void jbody(
    const C48& cb, const f32x2 zv[R][8], __half2 accH[R][8], float accJ[R],
    float JMUL, float JK) {
  f32x2 js2[R];
#pragma unroll
  for (int r = 0; r < R; ++r) js2[r] = (f32x2){0.0f, 0.0f};
#pragma unroll
  for (int p = 0; p < 8; ++p) {
#pragma unroll
    for (int r = 0; r < R; ++r) {
      f32x2 lp = __builtin_elementwise_fma(
          __builtin_elementwise_fma(cb.v[p], zv[r][p], cb.v[8 + p]),
          zv[r][p], cb.v[16 + p]);
      HU h;
      asm("v_cvt_pknorm_u16_f32 %0, %1, %2"
          : "=v"(h.u) : "v"(lp.x), "v"(lp.y));
      accH[r][p] = __hadd2(accH[r][p], h.h);
      js2[r] += lp;
    }
  }
#pragma unroll
  for (int r = 0; r < R; ++r) {
    float w = fmaf(js2[r].x + js2[r].y, JMUL, JK);
    unsigned u;
    asm("v_cvt_u32_f32 %0, %1" : "=v"(u) : "v"(w));    // neg saturates to 0
    accJ[r] += __uint_as_float(u);
  }
}

template <int CHUNK, int R>
__global__ __launch_bounds__(256, 2) void tc_kernel(
    const float* __restrict__ z, const float* __restrict__ coef,
    float* __restrict__ partial) {
  __shared__ float lcoef[CHUNK * 48];
  const int tid = threadIdx.x;
  const int i0 = blockIdx.x * (256 * R) + tid;
  const int j0 = blockIdx.y * CHUNK;
  const float JMUL = 65535.0f * 8192.0f;
  const float JK   = -SCALE23 * (16.0f * OFFC - BIASF);

  // Stage this block's coef chunk into LDS (coalesced float4 loads).
  {
    const float4* g4 = (const float4*)(coef + (size_t)j0 * 48);
    float4* l4 = (float4*)lcoef;
    for (int t = tid; t < (CHUNK * 48) / 4; t += 256) l4[t] = g4[t];
  }

  // z rows in registers as 8 f32 pairs per row; pinned (R4: compiler
  // otherwise sinks these loads into the j-loop).
  f32x2 zv[R][8];
#pragma unroll
  for (int r = 0; r < R; ++r) {
    const float4* zp = (const float4*)(z + (size_t)(i0 + 256 * r) * 16);
#pragma unroll
    for (int q = 0; q < 4; ++q) {
      float4 v = zp[q];
      zv[r][2 * q]     = (f32x2){v.x, v.y};
      zv[r][2 * q + 1] = (f32x2){v.z, v.w};
    }
  }
#pragma unroll
  for (int r = 0; r < R; ++r)
#pragma unroll
    for (int p = 0; p < 8; ++p) asm volatile("" : "+v"(zv[r][p]));

  __half2 accH[R][8];
#pragma unroll
  for (int r = 0; r < R; ++r)
#pragma unroll
    for (int p = 0; p < 8; ++p) { HU t; t.u = 0u; accH[r][p] = t.h; }
  float accJ[R];
#pragma unroll
  for (int r = 0; r < R; ++r) accJ[r] = 0.0f;

  __syncthreads();

  // Software-pipelined j-loop: named even/odd buffers, prefetch j+1 before
  // computing j. Wrap via mask (harmless re-read of row 0 at the tail).
  C48 bA, bB;
  ldcoef(bA, lcoef);
#pragma unroll 1
  for (int j = 0; j < CHUNK; j += 2) {
    ldcoef(bB, lcoef + ((j + 1) & (CHUNK - 1)) * 48);
    jbody<CHUNK, R>(bA, zv, accH, accJ, JMUL, JK);
    ldcoef(bA, lcoef + ((j + 2) & (CHUNK - 1)) * 48);
    jbody<CHUNK, R>(bB, zv, accH, accJ, JMUL, JK);
  }

  // Packed store: 8 raw f16-pair words + 1 f32 joint per (i, chunk).
#pragma unroll
  for (int r = 0; r < R; ++r) {
    const size_t b9 = ((size_t)blockIdx.y * 9) * BB + (size_t)(i0 + 256 * r);
    unsigned* up = (unsigned*)partial;
#pragma unroll
    for (int p = 0; p < 8; ++p) {
      HU t; t.h = accH[r][p];
      up[b9 + (size_t)p * BB] = t.u;
    }
    partial[b9 + (size_t)8 * BB] = accJ[r];
  }
}

// ---------------------------------------------------------------------------
// Kernel C: group-reduce packed partials. grid (16, G), G = nc/16; each block
// sums a 16-chunk group for 256 i's, unpacking f16 pairs -> 17 f32 planes.
// ---------------------------------------------------------------------------
__global__ __launch_bounds__(256) void reduce_kernel(
    const unsigned* __restrict__ partial, float* __restrict__ red2) {
  const int i = blockIdx.x * 256 + threadIdx.x;
  const int g = blockIdx.y;
  const unsigned* p = partial + ((size_t)g * 16 * 9) * BB + i;

  float s[17];
#pragma unroll
  for (int k = 0; k < 17; ++k) s[k] = 0.0f;

#pragma unroll 4
  for (int c = 0; c < 16; ++c) {
    const size_t cb = (size_t)c * 9 * BB;
#pragma unroll
    for (int q = 0; q < 8; ++q) {
      HU t; t.u = p[cb + (size_t)q * BB];
      s[2 * q]     += __low2float(t.h);
      s[2 * q + 1] += __high2float(t.h);
    }
    s[16] += __uint_as_float(p[cb + (size_t)8 * BB]);
  }

  float* r2 = red2 + ((size_t)g * 17) * BB + i;
#pragma unroll
  for (int k = 0; k < 16; ++k)
    r2[(size_t)k * BB] = s[k] * 0.00390625f;  // 2^-8 rescale to true exp2 sums
  r2[(size_t)16 * BB] = s[16];
}

// ---------------------------------------------------------------------------
// Kernel D: sum G group-planes, logs, fold recon/KL into out[0].
// ---------------------------------------------------------------------------
__global__ __launch_bounds__(256) void final_kernel(
    const float* __restrict__ red2, const float* __restrict__ rp,
    const float* __restrict__ klp, float* __restrict__ out, int G) {
  const int tid = threadIdx.x;
  const int i = blockIdx.x * 256 + tid;

  float acc[17];
#pragma unroll
  for (int k = 0; k < 17; ++k) acc[k] = 0.0f;
  for (int g = 0; g < G; ++g) {
    const float* r2 = red2 + ((size_t)g * 17) * BB + i;
#pragma unroll
    for (int k = 0; k < 17; ++k) acc[k] += r2[(size_t)k * BB];
  }

  float lg = LOG2(acc[16]);  // log2 S_joint
#pragma unroll
  for (int k = 0; k < 16; ++k) lg -= LOG2(acc[k]);
  float t = lg * (LN2_F / (float)BB);
  if (blockIdx.x == 0) {
#pragma unroll
    for (int q = 0; q < 8; ++q) t += rp[tid + 256 * q];
    t += klp[tid];
  }
  float s = block_reduce(t);
  if (tid == 0) atomicAdd(out, s);
}

extern "C" void kernel_launch(void* const* d_in, const int* in_sizes, int n_in,
                              void* d_out, int out_size, void* d_ws, size_t ws_size,
                              hipStream_t stream) {
  const float* data  = (const float*)d_in[0];
  const float* recon = (const float*)d_in[1];
  const float* z     = (const float*)d_in[2];
  const float* zm    = (const float*)d_in[3];
  const float* zlv   = (const float*)d_in[4];
  float* out = (float*)d_out;
  float* ws  = (float*)d_ws;

  const int nc = 128;  // CHUNK=32, grid (4,128) = 512 blocks = 2/CU
  const int G = nc / 16;

  float* coef = ws + COEF_F;
  float* rp   = ws + RP_F;
  float* klp  = ws + KLP_F;
  float* part = ws + PART_F;
  float* red2 = ws + PART_F + (size_t)nc * 9 * BB;

  hipLaunchKernelGGL(prep_recon_kernel, dim3(2048), dim3(256), 0, stream,
                     reinterpret_cast<const float4*>(data),
                     reinterpret_cast<const float4*>(recon),
                     zm, zlv, coef, rp, klp, out);
  hipLaunchKernelGGL((tc_kernel<32, 4>), dim3(4, 128), dim3(256), 0, stream,
                     z, coef, part);
  hipLaunchKernelGGL(reduce_kernel, dim3(BB / 256, G), dim3(256), 0, stream,
                     reinterpret_cast<const unsigned*>(part), red2);
  hipLaunchKernelGGL(final_kernel, dim3(BB / 256), dim3(256), 0, stream,
                     red2, rp, klp, out, G);
}

// Round 16
// 114.412 us; speedup vs baseline: 2.6732x; 1.0247x over previous
//
#include <hip/hip_runtime.h>
#include <hip/hip_fp16.h>
#include <math.h>

// Problem constants (fixed by reference setup_inputs)
#define BB 4096
#define LL 16
#define DD 512

// Marginal lookup table: 16 latents x NPTS points over [XMIN, XMIN+XRANGE]
#define NPTS   1024
#define XMIN   -6.0f
#define XRANGE 12.0f

#define LOG2E_F  1.4426950408889634f
#define LN2_F    0.6931471805599453f
#define LOG2PI_F 1.8378770664093453f

// Schraudolph f32 exp2 for the joint: w = 2^23*(lp2sum + BIASF); cvt_u32
// saturates negatives to 0; bits reinterpreted as f32 ~ 2^lp2sum.
#define SCALE23  8388608.0f
#define BIASF    126.94269504f

#if __has_builtin(__builtin_amdgcn_exp2f)
#define EXP2(x) __builtin_amdgcn_exp2f(x)
#else
#define EXP2(x) exp2f(x)
#endif
#if __has_builtin(__builtin_amdgcn_logf)
#define LOG2(x) __builtin_amdgcn_logf(x)
#else
#define LOG2(x) log2f(x)
#endif

typedef short bf16x8 __attribute__((ext_vector_type(8)));
typedef unsigned short u16x8 __attribute__((ext_vector_type(8)));
typedef float f32x16 __attribute__((ext_vector_type(16)));

// ws float-offset layout:
//   Wm  [0      , 262144)   bf16 [4096 j][128 k] split-coef matrix (1 MB)
//   Fm  [262144 , 524288)   bf16 [4096 i][128 k] split-feature matrix (1 MB)
//   ct  [524288 , 720896)   raw coefs transposed [part 3][l 16][j 4096]
//   rp  [720896 , 722944)   2048 recon block partials (pre-scaled)
//   klp [722944 , 723200)   256 KL block partials (pre-scaled)
//   tp  [723200 , 1247488)  table partials [jc 32][l 16][g 1024]
//   tab [1247488, 1263872)  marginal table [l 16][g 1024]
//   jp  [1263872, 1394944)  joint partials [chunk 32][i 4096]
#define WM_F   0
#define FM_F   262144
#define CT_F   524288
#define RP_F   720896
#define KLP_F  722944
#define TP_F   723200
#define TAB_F  1247488
#define JP_F   1263872

// Split x into bf16 hi (truncate) + bf16 lo (RNE of residual).
__device__ __forceinline__ void split_bf16(float x, unsigned short& h,
                                           unsigned short& l) {
  unsigned u = __float_as_uint(x);
  h = (unsigned short)(u >> 16);
  float hf = __uint_as_float((unsigned)h << 16);
  unsigned v = __float_as_uint(x - hf);
  unsigned r = v + 0x7FFFu + ((v >> 16) & 1u);
  l = (unsigned short)(r >> 16);
}

// Block-level sum reduction; result valid on thread 0. Re-entrant.
__device__ __forceinline__ float block_reduce(float v) {
  __shared__ float sm[4];
  __syncthreads();
#pragma unroll
  for (int off = 32; off; off >>= 1) v += __shfl_xor(v, off);
  if ((threadIdx.x & 63) == 0) sm[threadIdx.x >> 6] = v;
  __syncthreads();
  if (threadIdx.x == 0) v = (sm[0] + sm[1]) + (sm[2] + sm[3]);
  return v;
}

// ---------------------------------------------------------------------------
// Kernel A: recon partials + KL + out zero + W/F split-bf16 matrices + ct.
// lp2(i,j) = sum_l A_jl z_il^2 + B_jl z_il + C_jl  ==  W_j . f_i  with
// per-latent 8 K-slots: W=[Ah,Ah,Al,Bh,Bh,Bl,Ch,Cl], f=[x2h,x2l,x2h,xh,xl,
// xh,1,1] (dropped lo*lo terms ~2^-16 relative).
// ---------------------------------------------------------------------------
__global__ __launch_bounds__(256) void prep_recon_kernel(
    const float4* __restrict__ data4, const float4* __restrict__ recon4,
    const float* __restrict__ zm, const float* __restrict__ zlv,
    const float* __restrict__ z,
    unsigned short* __restrict__ Wm, unsigned short* __restrict__ Fm,
    float* __restrict__ ct, float* __restrict__ rp,
    float* __restrict__ klp, float* __restrict__ out) {
  const int tid = threadIdx.x;
  const int b = blockIdx.x;

  if (b == 1024 && tid == 0) out[0] = 0.0f;  // consumed by final_kernel later

  {
    const int n4 = (BB * DD) / 4;
    int stride = gridDim.x * 256;
    float s = 0.0f;
    for (int k = b * 256 + tid; k < n4; k += stride) {
      float4 a = data4[k];
      float4 r = recon4[k];
      s += (fabsf(a.x - r.x) + fabsf(a.y - r.y)) +
           (fabsf(a.z - r.z) + fabsf(a.w - r.w));
    }
    float t = block_reduce(s);
    if (tid == 0) rp[b] = t * (1.0f / (float)(BB * DD));
  }

  if (b < 256) {  // coefs: W row + ct + KL
    int idx = b * 256 + tid;
    int j = idx >> 4;
    int l = idx & 15;
    float m = zm[idx];
    float lv = zlv[idx];
    float inv = EXP2(-lv * LOG2E_F);           // e^{-lv}
    float a = -0.5f * LOG2E_F * inv;           // log2-domain quadratic coef
    float c2 = -0.5f * LOG2E_F * (lv + LOG2PI_F);
    float braw = -2.0f * a * m;
    float craw = fmaf(a, m * m, c2);

    unsigned short Ah, Al, Bh, Bl, Ch, Cl;
    split_bf16(a, Ah, Al);
    split_bf16(braw, Bh, Bl);
    split_bf16(craw, Ch, Cl);
    u16x8 wv8 = {Ah, Ah, Al, Bh, Bh, Bl, Ch, Cl};
    *(u16x8*)(Wm + (size_t)j * 128 + 8 * l) = wv8;

    ct[(0 * 16 + l) * 4096 + j] = a;
    ct[(1 * 16 + l) * 4096 + j] = braw;
    ct[(2 * 16 + l) * 4096 + j] = craw;

    float kls = m * m + EXP2(lv * LOG2E_F) - lv - 1.0f;
    float s = block_reduce(kls);
    if (tid == 0) klp[b] = s * (0.5f / (float)BB);
  } else if (b < 512) {  // features: F row from z
    int idx = (b - 256) * 256 + tid;
    int i = idx >> 4;
    int l = idx & 15;
    float x = z[idx];
    float x2 = x * x;
    unsigned short x2h, x2l, xh, xl;
    split_bf16(x2, x2h, x2l);
    split_bf16(x, xh, xl);
    u16x8 fv8 = {x2h, x2l, x2h, xh, xl, xh, 0x3F80, 0x3F80};  // 0x3F80=bf16 1.0
    *(u16x8*)(Fm + (size_t)i * 128 + 8 * l) = fv8;
  }
}

// ---------------------------------------------------------------------------
// Kernel B1: marginal table build (exact v_exp_f32). grid (32 jc, 16 l).
// ---------------------------------------------------------------------------
__global__ __launch_bounds__(256) void table_build(
    const float* __restrict__ ct, float* __restrict__ tpart) {
  __shared__ float la[128], lb[128], lc[128];
  const int tid = threadIdx.x;
  const int jc = blockIdx.x;
  const int l  = blockIdx.y;
  const int j0 = jc * 128;
  if (tid < 128) {
    la[tid] = ct[(0 * 16 + l) * 4096 + j0 + tid];
    lb[tid] = ct[(1 * 16 + l) * 4096 + j0 + tid];
    lc[tid] = ct[(2 * 16 + l) * 4096 + j0 + tid];
  }
  const float H = XRANGE / (float)(NPTS - 1);
  float x[4], acc[4];
#pragma unroll
  for (int k = 0; k < 4; ++k) {
    x[k] = XMIN + (float)(k * 256 + tid) * H;
    acc[k] = 0.0f;
  }
  __syncthreads();
#pragma unroll 2
  for (int j = 0; j < 128; ++j) {
    float a = la[j], bb = lb[j], c = lc[j];
#pragma unroll
    for (int k = 0; k < 4; ++k) {
      float lp = fmaf(fmaf(a, x[k], bb), x[k], c);
      acc[k] += EXP2(lp);
    }
  }
  float* o = tpart + ((size_t)jc * 16 + l) * NPTS;
#pragma unroll
  for (int k = 0; k < 4; ++k) o[k * 256 + tid] = acc[k];
}

// ---------------------------------------------------------------------------
// Kernel B2: sum the 32 jc-partials -> table[l][g]. grid 64 blocks.
// ---------------------------------------------------------------------------
__global__ __launch_bounds__(256) void table_reduce(
    const float* __restrict__ tpart, float* __restrict__ table) {
  const int e = blockIdx.x * 256 + threadIdx.x;
  float s = 0.0f;
#pragma unroll 4
  for (int jc = 0; jc < 32; ++jc) s += tpart[(size_t)jc * (16 * NPTS) + e];
  table[e] = s;
}

// ---------------------------------------------------------------------------
// Kernel C: MFMA joint. S = W (4096x128) x F^T -> per-pair lp2sum, fused
// Schraudolph-exp2 epilogue, summed over j per i.
// Session finding (R0-R15): the 32-iteration scalar j-loop has a ~1200cy/iter
// serialized wall invariant to body size; only ITERATION COUNT moves it.
// Here: 8 K-step mfma chain replaces 32 j-iters. Per wave: one 32-i tile,
// 4 j-tiles (blockIdx.y covers 128 j's). D-frag: col=lane&31 = i (verified
// layout), 16 regs = j-rows -> post-exp sum is LANE-LOCAL; xor-32 merges the
// two row-halves. A/B k-permutation cancels (identical addressing both sides).
// ---------------------------------------------------------------------------
__global__ __launch_bounds__(256, 4) void mfma_joint(
    const unsigned short* __restrict__ Wm,
    const unsigned short* __restrict__ Fm, float* __restrict__ jp) {
  const int tid = threadIdx.x;
  const int lane = tid & 63;
  const int wv = tid >> 6;
  const int i0 = blockIdx.x * 128 + wv * 32;   // this wave's 32-i tile
  const int jt0 = blockIdx.y * 4;              // 4 j-tiles (128 j's)
  const int r32 = lane & 31;
  const int khalf = (lane >> 5) * 8;           // k-offset within 16-step

  // Preload B-frags (this wave's i-features, full K): 8 x 16B.
  bf16x8 bfr[8];
  const unsigned short* frow = Fm + (size_t)(i0 + r32) * 128 + khalf;
#pragma unroll
  for (int s = 0; s < 8; ++s) bfr[s] = *(const bf16x8*)(frow + 16 * s);
#pragma unroll
  for (int s = 0; s < 8; ++s) asm volatile("" : "+v"(bfr[s]));

  const float KK = SCALE23 * BIASF;
  float accJ = 0.0f;

#pragma unroll
  for (int t = 0; t < 4; ++t) {
    const int j0 = (jt0 + t) * 32;
    const unsigned short* wrow = Wm + (size_t)(j0 + r32) * 128 + khalf;
    f32x16 acc;
#pragma unroll
    for (int e = 0; e < 16; ++e) acc[e] = 0.0f;
#pragma unroll
    for (int s = 0; s < 8; ++s) {
      bf16x8 af = *(const bf16x8*)(wrow + 16 * s);
      acc = __builtin_amdgcn_mfma_f32_32x32x16_bf16(af, bfr[s], acc, 0, 0, 0);
    }
    // Epilogue: lane holds 16 j-rows of col i -> Schraudolph exp2 + sum.
#pragma unroll
    for (int e = 0; e < 16; ++e) {
      float w = fmaf(acc[e], SCALE23, KK);     // 2^23*(lp2sum + BIASF)
      unsigned u;
      asm("v_cvt_u32_f32 %0, %1" : "=v"(u) : "v"(w));  // neg saturates to 0
      accJ += __uint_as_float(u);
    }
  }

  accJ += __shfl_xor(accJ, 32);  // merge the two row-halves of this col
  if (lane < 32)
    jp[(size_t)blockIdx.y * BB + (size_t)(i0 + r32)] = accJ;  // coalesced
}

// ---------------------------------------------------------------------------
// Kernel D: final. Sum 32 joint chunks per i, LDS-staged table interpolation
// for the 16 marginals, logs, fold recon/KL into out[0].
// ---------------------------------------------------------------------------
__global__ __launch_bounds__(256) void final_kernel(
    const float* __restrict__ z, const float* __restrict__ jp,
    const float* __restrict__ table, const float* __restrict__ rp,
    const float* __restrict__ klp, float* __restrict__ out) {
  __shared__ float ltab[16 * NPTS];  // 64 KB
  const int tid = threadIdx.x;
  const int i = blockIdx.x * 256 + tid;

  for (int t = tid; t < 16 * NPTS; t += 256) ltab[t] = table[t];

  float s0 = 0.0f, s1 = 0.0f, s2 = 0.0f, s3 = 0.0f;
#pragma unroll 8
  for (int c = 0; c < 32; c += 4) {
    s0 += jp[(size_t)(c + 0) * BB + i];
    s1 += jp[(size_t)(c + 1) * BB + i];
    s2 += jp[(size_t)(c + 2) * BB + i];
    s3 += jp[(size_t)(c + 3) * BB + i];
  }
  float lg = LOG2((s0 + s1) + (s2 + s3));  // log2 S_joint

  __syncthreads();  // table staged

  const float4* zp = (const float4*)(z + (size_t)i * 16);
  const float SC = (float)(NPTS - 1) / XRANGE;
#pragma unroll
  for (int q = 0; q < 4; ++q) {
    float4 v = zp[q];
    float xs[4] = {v.x, v.y, v.z, v.w};
#pragma unroll
    for (int k = 0; k < 4; ++k) {
      int l = 4 * q + k;
      float t = (xs[k] - XMIN) * SC;
      t = fminf(fmaxf(t, 0.0f), (float)(NPTS - 2) + 0.999f);
      int g = (int)t;
      float f = t - (float)g;
      float m0 = ltab[l * NPTS + g];
      float m1 = ltab[l * NPTS + g + 1];
      lg -= LOG2(fmaf(f, m1 - m0, m0));
    }
  }

  float tval = lg * (LN2_F / (float)BB);
  if (blockIdx.x == 0) {
#pragma unroll
    for (int q = 0; q < 8; ++q) tval += rp[tid + 256 * q];
    tval += klp[tid];
  }

  __syncthreads();  // all gathers done; safe to reuse ltab
#pragma unroll
  for (int off = 32; off; off >>= 1) tval += __shfl_xor(tval, off);
  if ((tid & 63) == 0) ltab[tid >> 6] = tval;
  __syncthreads();
  if (tid == 0) atomicAdd(out, (ltab[0] + ltab[1]) + (ltab[2] + ltab[3]));
}

extern "C" void kernel_launch(void* const* d_in, const int* in_sizes, int n_in,
                              void* d_out, int out_size, void* d_ws, size_t ws_size,
                              hipStream_t stream) {
  const float* data  = (const float*)d_in[0];
  const float* recon = (const float*)d_in[1];
  const float* z     = (const float*)d_in[2];
  const float* zm    = (const float*)d_in[3];
  const float* zlv   = (const float*)d_in[4];
  float* out = (float*)d_out;
  float* ws  = (float*)d_ws;

  unsigned short* Wm = (unsigned short*)(ws + WM_F);
  unsigned short* Fm = (unsigned short*)(ws + FM_F);
  float* ct  = ws + CT_F;
  float* rp  = ws + RP_F;
  float* klp = ws + KLP_F;
  float* tp  = ws + TP_F;
  float* tab = ws + TAB_F;
  float* jp  = ws + JP_F;

  hipLaunchKernelGGL(prep_recon_kernel, dim3(2048), dim3(256), 0, stream,
                     reinterpret_cast<const float4*>(data),
                     reinterpret_cast<const float4*>(recon),
                     zm, zlv, z, Wm, Fm, ct, rp, klp, out);
  hipLaunchKernelGGL(table_build, dim3(32, 16), dim3(256), 0, stream,
                     ct, tp);
  hipLaunchKernelGGL(table_reduce, dim3((16 * NPTS) / 256), dim3(256), 0,
                     stream, tp, tab);
  hipLaunchKernelGGL(mfma_joint, dim3(32, 32), dim3(256), 0, stream,
                     Wm, Fm, jp);
  hipLaunchKernelGGL(final_kernel, dim3(BB / 256), dim3(256), 0, stream,
                     z, jp, tab, rp, klp, out);
}

// Round 17
// 100.717 us; speedup vs baseline: 3.0367x; 1.1360x over previous
//
#include <hip/hip_runtime.h>
#include <hip/hip_fp16.h>
#include <math.h>

// Problem constants (fixed by reference setup_inputs)
#define BB 4096
#define LL 16
#define DD 512

// Marginal lookup table: 16 latents x NPTS points over [XMIN, XMIN+XRANGE]
#define NPTS   1024
#define XMIN   -6.0f
#define XRANGE 12.0f

#define LOG2E_F  1.4426950408889634f
#define LN2_F    0.6931471805599453f
#define LOG2PI_F 1.8378770664093453f

// Schraudolph f32 exp2 for the joint: w = 2^23*(lp2sum + BIASF); cvt_u32
// saturates negatives to 0; bits reinterpreted as f32 ~ 2^lp2sum.
#define SCALE23  8388608.0f
#define BIASF    126.94269504f

#if __has_builtin(__builtin_amdgcn_exp2f)
#define EXP2(x) __builtin_amdgcn_exp2f(x)
#else
#define EXP2(x) exp2f(x)
#endif
#if __has_builtin(__builtin_amdgcn_logf)
#define LOG2(x) __builtin_amdgcn_logf(x)
#else
#define LOG2(x) log2f(x)
#endif

typedef short bf16x8 __attribute__((ext_vector_type(8)));
typedef unsigned short u16x8 __attribute__((ext_vector_type(8)));
typedef float f32x16 __attribute__((ext_vector_type(16)));

// ws float-offset layout:
//   Wm  [0      , 262144)   bf16 FRAGMENT-MAJOR coef matrix (1 MB):
//                           slot[(jt*8+s)*64 + half*32 + (j&31)] of u16x8
//   Fm  [262144 , 524288)   bf16 FRAGMENT-MAJOR feature matrix (1 MB), same
//   ct  [524288 , 720896)   raw coefs transposed [part 3][l 16][j 4096]
//   rp  [720896 , 722944)   2048 recon block partials (pre-scaled)
//   klp [722944 , 723200)   256 KL block partials (pre-scaled)
//   tp  [723200 , 1247488)  table partials [jc 32][l 16][g 1024]
//   tab [1247488, 1263872)  marginal table [l 16][g 1024]
//   jp  [1263872, 1394944)  joint partials [chunk 32][i 4096]
#define WM_F   0
#define FM_F   262144
#define CT_F   524288
#define RP_F   720896
#define KLP_F  722944
#define TP_F   723200
#define TAB_F  1247488
#define JP_F   1263872

// Split x into bf16 hi (truncate) + bf16 lo (RNE of residual).
__device__ __forceinline__ void split_bf16(float x, unsigned short& h,
                                           unsigned short& l) {
  unsigned u = __float_as_uint(x);
  h = (unsigned short)(u >> 16);
  float hf = __uint_as_float((unsigned)h << 16);
  unsigned v = __float_as_uint(x - hf);
  unsigned r = v + 0x7FFFu + ((v >> 16) & 1u);
  l = (unsigned short)(r >> 16);
}

// Block-level sum reduction; result valid on thread 0. Re-entrant.
__device__ __forceinline__ float block_reduce(float v) {
  __shared__ float sm[4];
  __syncthreads();
#pragma unroll
  for (int off = 32; off; off >>= 1) v += __shfl_xor(v, off);
  if ((threadIdx.x & 63) == 0) sm[threadIdx.x >> 6] = v;
  __syncthreads();
  if (threadIdx.x == 0) v = (sm[0] + sm[1]) + (sm[2] + sm[3]);
  return v;
}

// ---------------------------------------------------------------------------
// Kernel A: recon partials + KL + out zero + W/F split-bf16 matrices + ct.
// lp2(i,j) = W_j . f_i, per-latent 8 K-slots: W=[Ah,Ah,Al,Bh,Bh,Bl,Ch,Cl],
// f=[x2h,x2l,x2h,xh,xl,xh,1,1] (dropped lo*lo ~2^-16 relative).
// FRAGMENT-MAJOR store (R16 fix): R16's row-major layout made each wave-load
// in mfma_joint touch 32 distinct cache lines (lane reads row j0+(lane&31),
// 256B stride) -> ~670 MB of L2 line traffic grid-wide for 2 MB of data.
// Fragment-major packs each (tile jt, k-step s) wave-fragment contiguously:
//   slot = (jt*8 + s)*64 + half*32 + row32,  16B per lane -> 1KB coalesced.
// Mapping from (j,l): k0=8l -> s=l>>1, half=l&1, row32=j&31. Data per lane
// identical to R16 (which PASSED, absmax 0) — addressing-only change.
// ---------------------------------------------------------------------------
__global__ __launch_bounds__(256) void prep_recon_kernel(
    const float4* __restrict__ data4, const float4* __restrict__ recon4,
    const float* __restrict__ zm, const float* __restrict__ zlv,
    const float* __restrict__ z,
    unsigned short* __restrict__ Wm, unsigned short* __restrict__ Fm,
    float* __restrict__ ct, float* __restrict__ rp,
    float* __restrict__ klp, float* __restrict__ out) {
  const int tid = threadIdx.x;
  const int b = blockIdx.x;

  if (b == 1024 && tid == 0) out[0] = 0.0f;  // consumed by final_kernel later

  {
    const int n4 = (BB * DD) / 4;
    int stride = gridDim.x * 256;
    float s = 0.0f;
    for (int k = b * 256 + tid; k < n4; k += stride) {
      float4 a = data4[k];
      float4 r = recon4[k];
      s += (fabsf(a.x - r.x) + fabsf(a.y - r.y)) +
           (fabsf(a.z - r.z) + fabsf(a.w - r.w));
    }
    float t = block_reduce(s);
    if (tid == 0) rp[b] = t * (1.0f / (float)(BB * DD));
  }

  if (b < 256) {  // coefs: W fragments + ct + KL
    int idx = b * 256 + tid;
    int j = idx >> 4;
    int l = idx & 15;
    float m = zm[idx];
    float lv = zlv[idx];
    float inv = EXP2(-lv * LOG2E_F);           // e^{-lv}
    float a = -0.5f * LOG2E_F * inv;           // log2-domain quadratic coef
    float c2 = -0.5f * LOG2E_F * (lv + LOG2PI_F);
    float braw = -2.0f * a * m;
    float craw = fmaf(a, m * m, c2);

    unsigned short Ah, Al, Bh, Bl, Ch, Cl;
    split_bf16(a, Ah, Al);
    split_bf16(braw, Bh, Bl);
    split_bf16(craw, Ch, Cl);
    u16x8 wv8 = {Ah, Ah, Al, Bh, Bh, Bl, Ch, Cl};
    size_t slot = ((size_t)(j >> 5) * 8 + (l >> 1)) * 64 + (l & 1) * 32 + (j & 31);
    *(u16x8*)(Wm + slot * 8) = wv8;

    ct[(0 * 16 + l) * 4096 + j] = a;
    ct[(1 * 16 + l) * 4096 + j] = braw;
    ct[(2 * 16 + l) * 4096 + j] = craw;

    float kls = m * m + EXP2(lv * LOG2E_F) - lv - 1.0f;
    float s = block_reduce(kls);
    if (tid == 0) klp[b] = s * (0.5f / (float)BB);
  } else if (b < 512) {  // features: F fragments from z
    int idx = (b - 256) * 256 + tid;
    int i = idx >> 4;
    int l = idx & 15;
    float x = z[idx];
    float x2 = x * x;
    unsigned short x2h, x2l, xh, xl;
    split_bf16(x2, x2h, x2l);
    split_bf16(x, xh, xl);
    u16x8 fv8 = {x2h, x2l, x2h, xh, xl, xh, 0x3F80, 0x3F80};  // 0x3F80=bf16 1.0
    size_t slot = ((size_t)(i >> 5) * 8 + (l >> 1)) * 64 + (l & 1) * 32 + (i & 31);
    *(u16x8*)(Fm + slot * 8) = fv8;
  }
}

// ---------------------------------------------------------------------------
// Kernel B1: marginal table build (exact v_exp_f32). grid (32 jc, 16 l).
// ---------------------------------------------------------------------------
__global__ __launch_bounds__(256) void table_build(
    const float* __restrict__ ct, float* __restrict__ tpart) {
  __shared__ float la[128], lb[128], lc[128];
  const int tid = threadIdx.x;
  const int jc = blockIdx.x;
  const int l  = blockIdx.y;
  const int j0 = jc * 128;
  if (tid < 128) {
    la[tid] = ct[(0 * 16 + l) * 4096 + j0 + tid];
    lb[tid] = ct[(1 * 16 + l) * 4096 + j0 + tid];
    lc[tid] = ct[(2 * 16 + l) * 4096 + j0 + tid];
  }
  const float H = XRANGE / (float)(NPTS - 1);
  float x[4], acc[4];
#pragma unroll
  for (int k = 0; k < 4; ++k) {
    x[k] = XMIN + (float)(k * 256 + tid) * H;
    acc[k] = 0.0f;
  }
  __syncthreads();
#pragma unroll 2
  for (int j = 0; j < 128; ++j) {
    float a = la[j], bb = lb[j], c = lc[j];
#pragma unroll
    for (int k = 0; k < 4; ++k) {
      float lp = fmaf(fmaf(a, x[k], bb), x[k], c);
      acc[k] += EXP2(lp);
    }
  }
  float* o = tpart + ((size_t)jc * 16 + l) * NPTS;
#pragma unroll
  for (int k = 0; k < 4; ++k) o[k * 256 + tid] = acc[k];
}

// ---------------------------------------------------------------------------
// Kernel B2: sum the 32 jc-partials -> table[l][g]. grid 64 blocks.
// ---------------------------------------------------------------------------
__global__ __launch_bounds__(256) void table_reduce(
    const float* __restrict__ tpart, float* __restrict__ table) {
  const int e = blockIdx.x * 256 + threadIdx.x;
  float s = 0.0f;
#pragma unroll 4
  for (int jc = 0; jc < 32; ++jc) s += tpart[(size_t)jc * (16 * NPTS) + e];
  table[e] = s;
}

// ---------------------------------------------------------------------------
// Kernel C: MFMA joint, fragment-major coalesced loads.
// Per wave: one 32-i tile, 4 j-tiles; 8 K-step mfma_f32_32x32x16_bf16 chain
// per tile; Schraudolph exp2 epilogue summed over j per i (D col=lane&31=i,
// verified by R16's absmax=0). All fragment loads are now contiguous 1KB
// wave transactions (was: 32 cache lines per load in R16).
// ---------------------------------------------------------------------------
__global__ __launch_bounds__(256, 4) void mfma_joint(
    const unsigned short* __restrict__ Wm,
    const unsigned short* __restrict__ Fm, float* __restrict__ jp) {
  const int tid = threadIdx.x;
  const int lane = tid & 63;
  const int wv = tid >> 6;
  const int it = blockIdx.x * 4 + wv;          // this wave's 32-i tile
  const int i0 = it * 32;
  const int jt0 = blockIdx.y * 4;              // 4 j-tiles (128 j's)
  const int r32 = lane & 31;

  // Preload B-frags (this wave's i-features, full K): 8 coalesced 1KB loads.
  bf16x8 bfr[8];
#pragma unroll
  for (int s = 0; s < 8; ++s)
    bfr[s] = *(const bf16x8*)(Fm + (((size_t)it * 8 + s) * 64 + lane) * 8);
#pragma unroll
  for (int s = 0; s < 8; ++s) asm volatile("" : "+v"(bfr[s]));

  const float KK = SCALE23 * BIASF;
  float accJ = 0.0f;

#pragma unroll
  for (int t = 0; t < 4; ++t) {
    const int jt = jt0 + t;
    f32x16 acc;
#pragma unroll
    for (int e = 0; e < 16; ++e) acc[e] = 0.0f;
#pragma unroll
    for (int s = 0; s < 8; ++s) {
      bf16x8 af =
          *(const bf16x8*)(Wm + (((size_t)jt * 8 + s) * 64 + lane) * 8);
      acc = __builtin_amdgcn_mfma_f32_32x32x16_bf16(af, bfr[s], acc, 0, 0, 0);
    }
    // Epilogue: lane holds 16 j-rows of col i -> Schraudolph exp2 + sum.
#pragma unroll
    for (int e = 0; e < 16; ++e) {
      float w = fmaf(acc[e], SCALE23, KK);     // 2^23*(lp2sum + BIASF)
      unsigned u;
      asm("v_cvt_u32_f32 %0, %1" : "=v"(u) : "v"(w));  // neg saturates to 0
      accJ += __uint_as_float(u);
    }
  }

  accJ += __shfl_xor(accJ, 32);  // merge the two row-halves of this col
  if (lane < 32)
    jp[(size_t)blockIdx.y * BB + (size_t)(i0 + r32)] = accJ;  // coalesced
}

// ---------------------------------------------------------------------------
// Kernel D: final. Sum 32 joint chunks per i, LDS-staged table interpolation
// for the 16 marginals, logs, fold recon/KL into out[0].
// ---------------------------------------------------------------------------
__global__ __launch_bounds__(256) void final_kernel(
    const float* __restrict__ z, const float* __restrict__ jp,
    const float* __restrict__ table, const float* __restrict__ rp,
    const float* __restrict__ klp, float* __restrict__ out) {
  __shared__ float ltab[16 * NPTS];  // 64 KB
  const int tid = threadIdx.x;
  const int i = blockIdx.x * 256 + tid;

  for (int t = tid; t < 16 * NPTS; t += 256) ltab[t] = table[t];

  float s0 = 0.0f, s1 = 0.0f, s2 = 0.0f, s3 = 0.0f;
#pragma unroll 8
  for (int c = 0; c < 32; c += 4) {
    s0 += jp[(size_t)(c + 0) * BB + i];
    s1 += jp[(size_t)(c + 1) * BB + i];
    s2 += jp[(size_t)(c + 2) * BB + i];
    s3 += jp[(size_t)(c + 3) * BB + i];
  }
  float lg = LOG2((s0 + s1) + (s2 + s3));  // log2 S_joint

  __syncthreads();  // table staged

  const float4* zp = (const float4*)(z + (size_t)i * 16);
  const float SC = (float)(NPTS - 1) / XRANGE;
#pragma unroll
  for (int q = 0; q < 4; ++q) {
    float4 v = zp[q];
    float xs[4] = {v.x, v.y, v.z, v.w};
#pragma unroll
    for (int k = 0; k < 4; ++k) {
      int l = 4 * q + k;
      float t = (xs[k] - XMIN) * SC;
      t = fminf(fmaxf(t, 0.0f), (float)(NPTS - 2) + 0.999f);
      int g = (int)t;
      float f = t - (float)g;
      float m0 = ltab[l * NPTS + g];
      float m1 = ltab[l * NPTS + g + 1];
      lg -= LOG2(fmaf(f, m1 - m0, m0));
    }
  }

  float tval = lg * (LN2_F / (float)BB);
  if (blockIdx.x == 0) {
#pragma unroll
    for (int q = 0; q < 8; ++q) tval += rp[tid + 256 * q];
    tval += klp[tid];
  }

  __syncthreads();  // all gathers done; safe to reuse ltab
#pragma unroll
  for (int off = 32; off; off >>= 1) tval += __shfl_xor(tval, off);
  if ((tid & 63) == 0) ltab[tid >> 6] = tval;
  __syncthreads();
  if (tid == 0) atomicAdd(out, (ltab[0] + ltab[1]) + (ltab[2] + ltab[3]));
}

extern "C" void kernel_launch(void* const* d_in, const int* in_sizes, int n_in,
                              void* d_out, int out_size, void* d_ws, size_t ws_size,
                              hipStream_t stream) {
  const float* data  = (const float*)d_in[0];
  const float* recon = (const float*)d_in[1];
  const float* z     = (const float*)d_in[2];
  const float* zm    = (const float*)d_in[3];
  const float* zlv   = (const float*)d_in[4];
  float* out = (float*)d_out;
  float* ws  = (float*)d_ws;

  unsigned short* Wm = (unsigned short*)(ws + WM_F);
  unsigned short* Fm = (unsigned short*)(ws + FM_F);
  float* ct  = ws + CT_F;
  float* rp  = ws + RP_F;
  float* klp = ws + KLP_F;
  float* tp  = ws + TP_F;
  float* tab = ws + TAB_F;
  float* jp  = ws + JP_F;

  hipLaunchKernelGGL(prep_recon_kernel, dim3(2048), dim3(256), 0, stream,
                     reinterpret_cast<const float4*>(data),
                     reinterpret_cast<const float4*>(recon),
                     zm, zlv, z, Wm, Fm, ct, rp, klp, out);
  hipLaunchKernelGGL(table_build, dim3(32, 16), dim3(256), 0, stream,
                     ct, tp);
  hipLaunchKernelGGL(table_reduce, dim3((16 * NPTS) / 256), dim3(256), 0,
                     stream, tp, tab);
  hipLaunchKernelGGL(mfma_joint, dim3(32, 32), dim3(256), 0, stream,
                     Wm, Fm, jp);
  hipLaunchKernelGGL(final_kernel, dim3(BB / 256), dim3(256), 0, stream,
                     z, jp, tab, rp, klp, out);
}